// Round 12
// baseline (1132.276 us; speedup 1.0000x reference)
//
#include <hip/hip_runtime.h>
#include <math.h>

#define NX 8192
#define NY 65536
#define DIM 512
#define KNN 8

#define BMT 256                // Y rows per tile (MFMA M side)
#define BNT 256                // X rows per block (MFMA N side)
#define CHUNK 2048             // Y rows streamed per block
#define TILES (CHUNK / BMT)    // 8
#define NCHUNKS (NY / CHUNK)   // 32
#define LPT 6                  // per-lane top-K (packed keys)
#define KEEP 8                 // kept per (row, chunk)
#define NCAND (NCHUNKS * KEEP) // 256 per row (rescore unchanged)
#define RESC 32                // rescored per row

typedef short bf16x8 __attribute__((ext_vector_type(8)));
typedef float f32x4 __attribute__((ext_vector_type(4)));

#define AS1(p) (const __attribute__((address_space(1))) void*)(p)
#define AS3(p) (__attribute__((address_space(3))) void*)(p)

__device__ __forceinline__ unsigned short f2b(float f) {
    unsigned int u = __float_as_uint(f);
    u += 0x7FFFu + ((u >> 16) & 1u);       // RNE to bf16
    return (unsigned short)(u >> 16);
}

__device__ __forceinline__ unsigned int umin_(unsigned int a, unsigned int b) { return a < b ? a : b; }
__device__ __forceinline__ unsigned int umax_(unsigned int a, unsigned int b) { return a > b ? a : b; }

// branchless sorted-insert (ascending): 2 ops/slot, no divergence.
// l'[0]=min(l[0],x); l'[i]=min(max(x,l[i-1]), l[i]).
template <int K>
__device__ __forceinline__ void pushk_b(unsigned int x, unsigned int (&l)[K]) {
    unsigned int prev = l[0];
    l[0] = umin_(l[0], x);
#pragma unroll
    for (int i = 1; i < K; ++i) {
        unsigned int cur = l[i];
        l[i] = umin_(umax_(x, prev), cur);
        prev = cur;
    }
}

// branchy insert (serial contexts: cheap reject dominates, no divergence issue)
template <int K>
__device__ __forceinline__ void pushk(unsigned int k, unsigned int (&lst)[K]) {
    if (k >= lst[K - 1]) return;
    lst[K - 1] = k;
#pragma unroll
    for (int p = K - 1; p > 0; --p) {
        if (lst[p] < lst[p - 1]) {
            unsigned int t = lst[p]; lst[p] = lst[p - 1]; lst[p - 1] = t;
        }
    }
}

template <int K>
__device__ __forceinline__ void push(float d, int gi, float (&bd)[K], int (&bi)[K]) {
    if (d > bd[K - 1] || (d == bd[K - 1] && gi >= bi[K - 1])) return;
    bd[K - 1] = d; bi[K - 1] = gi;
#pragma unroll
    for (int p = K - 1; p > 0; --p) {
        bool sw = (bd[p] < bd[p - 1]) || (bd[p] == bd[p - 1] && bi[p] < bi[p - 1]);
        if (sw) {
            float td = bd[p]; bd[p] = bd[p - 1]; bd[p - 1] = td;
            int   ti = bi[p]; bi[p] = bi[p - 1]; bi[p - 1] = ti;
        }
    }
}

__global__ void cvt_bf16_kernel(const float* __restrict__ src,
                                unsigned short* __restrict__ dst, int n8) {
    int i = blockIdx.x * blockDim.x + threadIdx.x;
    if (i >= n8) return;
    const float4* s = (const float4*)src;
    float4 a0 = s[i * 2], a1 = s[i * 2 + 1];
    bf16x8 h;
    h[0] = (short)f2b(a0.x); h[1] = (short)f2b(a0.y);
    h[2] = (short)f2b(a0.z); h[3] = (short)f2b(a0.w);
    h[4] = (short)f2b(a1.x); h[5] = (short)f2b(a1.y);
    h[6] = (short)f2b(a1.z); h[7] = (short)f2b(a1.w);
    *(bf16x8*)(dst + (size_t)i * 8) = h;
}

__global__ void ysq_kernel(const float* __restrict__ Y, float* __restrict__ ysq) {
    int row  = (blockIdx.x * blockDim.x + threadIdx.x) >> 6;
    int lane = threadIdx.x & 63;
    if (row >= NY) return;
    const float4* yr = reinterpret_cast<const float4*>(Y + (size_t)row * DIM);
    double s = 0.0;
#pragma unroll
    for (int i = 0; i < 2; ++i) {
        float4 v = yr[lane + 64 * i];
        s += (double)v.x * v.x + (double)v.y * v.y + (double)v.z * v.z + (double)v.w * v.w;
    }
#pragma unroll
    for (int off = 32; off > 0; off >>= 1) s += __shfl_xor(s, off, 64);
    if (lane == 0) ysq[row] = (float)s;
}

// Coarse: 256x256 tile, 8 waves (2m x 4n), 128x64 per wave, 128 KB LDS dbuf,
// one barrier per K-step, branchless packed-key top-6 per lane list.
__global__ __launch_bounds__(512, 2) void knn_coarse_fast(
        const unsigned short* __restrict__ Xb, const unsigned short* __restrict__ Yb,
        const float* __restrict__ ysq,
        unsigned int* __restrict__ cand_k) {
    // [0,64K) As dbuf = 2 x [256 rows][128 B] Y tiles (source-swizzled);
    // [64K,128K) Bs dbuf = X tiles. Merge reuses [0, 50.2K).
    __shared__ __align__(16) char smem[131072];
    char* As = smem;
    char* Bs = smem + 65536;

    const int tid  = threadIdx.x;
    const int lane = tid & 63;
    const int w    = tid >> 6;               // 0..7
    const int l15  = lane & 15;
    const int lg   = lane >> 4;              // 0..3
    const int xcd  = blockIdx.x;             // 0..7 (linear%8 == blockIdx.x)
    const int xsub = blockIdx.y;             // 0..3
    const int zc   = blockIdx.z;             // 0..31 (candidate slot)
    const int row0  = (xcd * 4 + xsub) * BNT;   // X tile (4 per XCD -> 1 MB L2)
    const int ybase = zc * CHUNK;
    const int m0 = (w >> 2) * 128;           // wave quadrant: Y side (2)
    const int n0 = (w & 3) * 64;             //                X side (4)

    // staging geometry (proven r5-11): lane covers 16 B; 8 insts/wave/K-step
    const int srow = lane >> 3;                     // 0..7
    const int scb  = ((lane & 7) ^ srow) << 4;      // swizzled source chunk
    const char* pXbase = (const char*)Xb
        + ((size_t)(row0 + w * 32 + srow) << 10) + scb;

#define STAGE(tt, kcc, buf)                                                      \
    {                                                                            \
        const char* pY_ = (const char*)Yb                                        \
            + ((size_t)(ybase + (tt) * BMT + w * 32 + srow) << 10)               \
            + ((kcc) << 7) + scb;                                                \
        const char* pX_ = pXbase + ((kcc) << 7);                                 \
        char* dA_ = As + ((buf) << 15) + (w << 12);                              \
        char* dB_ = Bs + ((buf) << 15) + (w << 12);                              \
        _Pragma("unroll")                                                        \
        for (int q = 0; q < 4; ++q) {                                            \
            __builtin_amdgcn_global_load_lds(AS1(pY_ + ((size_t)(q * 8) << 10)), \
                                             AS3(dA_ + (q << 10)), 16, 0, 0);    \
            __builtin_amdgcn_global_load_lds(AS1(pX_ + ((size_t)(q * 8) << 10)), \
                                             AS3(dB_ + (q << 10)), 16, 0, 0);    \
        }                                                                        \
    }

    unsigned int kb_[4][LPT];
#pragma unroll
    for (int nf = 0; nf < 4; ++nf)
#pragma unroll
        for (int m = 0; m < LPT; ++m) kb_[nf][m] = 0xffffffffu;

    STAGE(0, 0, 0);   // prologue: 8 loads in flight

    for (int t = 0; t < TILES; ++t) {
        const int ytile0 = ybase + t * BMT;

        f32x4 acc[8][4];
#pragma unroll
        for (int i = 0; i < 8; ++i)
#pragma unroll
            for (int j = 0; j < 4; ++j) acc[i][j] = (f32x4){0.f, 0.f, 0.f, 0.f};

#pragma unroll
        for (int kc = 0; kc < 8; ++kc) {
            const int buf = kc & 1;
            // own staged slices landed -> barrier makes all slices visible;
            // all waves' buf^1 reads (kc-1) precede their barrier entry.
            asm volatile("s_waitcnt vmcnt(0)" ::: "memory");
            __builtin_amdgcn_sched_barrier(0);
            __builtin_amdgcn_s_barrier();
            if (kc < 7) {
                STAGE(t, kc + 1, buf ^ 1);
            } else if (t + 1 < TILES) {
                STAGE(t + 1, 0, buf ^ 1);
            }

            const char* Ab = As + (buf << 15);
            const char* Bb = Bs + (buf << 15);
#pragma unroll
            for (int kk = 0; kk < 2; ++kk) {
                const int kbyte = kk * 64 + lg * 16;
                const int sw = kbyte ^ ((l15 & 7) << 4);
                bf16x8 bfr[4];
#pragma unroll
                for (int nf = 0; nf < 4; ++nf)
                    bfr[nf] = *(const bf16x8*)(Bb + ((n0 + nf * 16 + l15) << 7) + sw);
                __builtin_amdgcn_s_setprio(1);
#pragma unroll
                for (int mf = 0; mf < 8; ++mf) {
                    bf16x8 af = *(const bf16x8*)(Ab + ((m0 + mf * 16 + l15) << 7) + sw);
#pragma unroll
                    for (int nf = 0; nf < 4; ++nf)
                        acc[mf][nf] = __builtin_amdgcn_mfma_f32_16x16x32_bf16(
                            af, bfr[nf], acc[mf][nf], 0, 0, 0);
                }
                __builtin_amdgcn_s_setprio(0);
            }
        }

        // epilogue: keys = (trunc(32*(ysq - 2*dot)) << 16) | yi  (yi < 2^16)
#pragma unroll
        for (int mf = 0; mf < 8; ++mf) {
            const int gib = ytile0 + m0 + mf * 16 + lg * 4;
            const float4 yq = *(const float4*)(ysq + gib);
            float yq32[4] = {yq.x * 32.f, yq.y * 32.f, yq.z * 32.f, yq.w * 32.f};
#pragma unroll
            for (int nf = 0; nf < 4; ++nf) {
#pragma unroll
                for (int j = 0; j < 4; ++j) {
                    float d32 = fmaf(acc[mf][nf][j], -64.f, yq32[j]);
                    d32 = fminf(fmaxf(d32, 0.f), 65535.f);
                    pushk_b<LPT>(((unsigned int)d32 << 16) | (unsigned int)(gib + j),
                                 kb_[nf]);
                }
            }
        }
    }
#undef STAGE

    // ---- merge 8 lane-lists per X row (reuses smem) ----
    __syncthreads();
    unsigned int* mbuf = (unsigned int*)smem;   // 256 rows x 49 dwords = 50 KB
    const int slot = (w >> 2) * 4 + lg;         // 0..7
#pragma unroll
    for (int nf = 0; nf < 4; ++nf) {
        const int r = n0 + nf * 16 + l15;
#pragma unroll
        for (int e = 0; e < LPT; ++e)
            mbuf[r * 49 + slot * LPT + e] = kb_[nf][e];
    }
    __syncthreads();
    if (tid < 256) {
        unsigned int mk[KEEP];
#pragma unroll
        for (int m = 0; m < KEEP; ++m) mk[m] = 0xffffffffu;
        for (int s2 = 0; s2 < 8; ++s2)
#pragma unroll
            for (int e = 0; e < LPT; ++e)
                pushk_b<KEEP>(mbuf[tid * 49 + s2 * LPT + e], mk);
        const int row = row0 + tid;
        unsigned int* co = cand_k + (size_t)row * NCAND + zc * KEEP;
#pragma unroll
        for (int m = 0; m < KEEP; ++m) co[m] = mk[m];
    }
}

// Rescore: coarse top-32 of 256 packed keys, then BIT-EXACT round-1 arithmetic.
__global__ __launch_bounds__(256) void knn_rescore(
        const float* __restrict__ X, const float* __restrict__ Y,
        const float* __restrict__ ysq,
        const unsigned int* __restrict__ cand_k,
        int* __restrict__ out) {
    __shared__ unsigned int ck[8][NCAND];
    __shared__ int   rci[8][RESC];
    __shared__ float rd[8][RESC];

    const int tid  = threadIdx.x;
    const int row0 = blockIdx.x * 8;

#pragma unroll
    for (int q = 0; q < 8; ++q) {
        const int idx = q * 256 + tid;       // 0..2047
        const int r = idx >> 8, j = idx & 255;
        ck[r][j] = cand_k[(size_t)(row0 + r) * NCAND + j];
    }
    __syncthreads();

    if (tid < 8) {
        unsigned int mk[RESC];
#pragma unroll
        for (int m = 0; m < RESC; ++m) mk[m] = 0xffffffffu;
        for (int j = 0; j < NCAND; ++j) pushk<RESC>(ck[tid][j], mk);
#pragma unroll
        for (int m = 0; m < RESC; ++m) rci[tid][m] = (int)(mk[m] & 0xffffu);
    }
    __syncthreads();

    {
        const int r = tid >> 5, c = tid & 31;
        const int row = row0 + r;
        const int yi = rci[r][c];
        const float* xr = X + (size_t)row * DIM;
        const float* yr = Y + (size_t)yi * DIM;
        double acc64 = 0.0;
        for (int kc = 0; kc < DIM; kc += 64) {
            float acc = 0.f;
#pragma unroll
            for (int k4 = 0; k4 < 16; ++k4) {
                float4 xv = *(const float4*)(xr + kc + k4 * 4);
                float4 yv = *(const float4*)(yr + kc + k4 * 4);
                acc = fmaf(xv.x, yv.x, acc);
                acc = fmaf(xv.y, yv.y, acc);
                acc = fmaf(xv.z, yv.z, acc);
                acc = fmaf(xv.w, yv.w, acc);
            }
            acc64 += (double)acc;
        }
        rd[r][c] = (float)((double)ysq[yi] - 2.0 * acc64);
    }
    __syncthreads();

    if (tid < 8) {
        float fd[KNN]; int fi[KNN];
#pragma unroll
        for (int m = 0; m < KNN; ++m) { fd[m] = INFINITY; fi[m] = 0x7fffffff; }
        for (int j = 0; j < RESC; ++j) push<KNN>(rd[tid][j], rci[tid][j], fd, fi);
        const int row = row0 + tid;
#pragma unroll
        for (int m = 0; m < KNN; ++m) out[row * KNN + m] = fi[m];
    }
}

extern "C" void kernel_launch(void* const* d_in, const int* in_sizes, int n_in,
                              void* d_out, int out_size, void* d_ws, size_t ws_size,
                              hipStream_t stream) {
    const float* X = (const float*)d_in[0];   // [8192, 512]
    const float* Y = (const float*)d_in[1];   // [65536, 512]
    int* out = (int*)d_out;                   // [8192, 8] int32

    char* ws = (char*)d_ws;
    float* ysq           = (float*)ws;                              // 256 KB
    unsigned int* cand_k = (unsigned int*)(ws + 262144);            // 8 MB
    size_t off = 262144 + (size_t)NX * NCAND * 4;
    unsigned short* Xbf = (unsigned short*)(ws + off);              // 8 MB
    unsigned short* Ybf = (unsigned short*)(ws + off + (size_t)NX * DIM * 2);  // 64 MB

    ysq_kernel<<<NY / 4, 256, 0, stream>>>(Y, ysq);
    cvt_bf16_kernel<<<(NX * DIM / 8) / 256, 256, 0, stream>>>(X, Xbf, NX * DIM / 8);
    cvt_bf16_kernel<<<(NY * DIM / 8) / 256, 256, 0, stream>>>(Y, Ybf, NY * DIM / 8);

    dim3 g1(8, 4, 32);   // 1024 blocks, 1/CU; linear%8 = blockIdx.x = xcd
    knn_coarse_fast<<<g1, 512, 0, stream>>>(Xbf, Ybf, ysq, cand_k);

    knn_rescore<<<NX / 8, 256, 0, stream>>>(X, Y, ysq, cand_k, out);
}

// Round 13
// 870.530 us; speedup vs baseline: 1.3007x; 1.3007x over previous
//
#include <hip/hip_runtime.h>
#include <math.h>

#define NX 8192
#define NY 65536
#define DIM 512
#define KNN 8

#define BM 128                 // Y rows per tile (MFMA M side)
#define BN 128                 // X rows per block (MFMA N side)
#define COLS_PER_CHUNK 2048    // Y rows streamed per block
#define TILES (COLS_PER_CHUNK / BM)           // 16
#define NSEG 8                 // Y segments (s>>3)
#define NZ 4                   // Y sub-segments (grid.z)
#define LPT 6                  // per-lane top-K (packed keys, branchless)
#define KEEP 8                 // kept per (row, slot)
#define NCAND (NSEG * NZ * KEEP)              // 256 per row (rescore unchanged)
#define RESC 32                // rescored per row

typedef short bf16x8 __attribute__((ext_vector_type(8)));
typedef float f32x4 __attribute__((ext_vector_type(4)));

#define AS1(p) (const __attribute__((address_space(1))) void*)(p)
#define AS3(p) (__attribute__((address_space(3))) void*)(p)

__device__ __forceinline__ unsigned short f2b(float f) {
    unsigned int u = __float_as_uint(f);
    u += 0x7FFFu + ((u >> 16) & 1u);       // RNE to bf16
    return (unsigned short)(u >> 16);
}

__device__ __forceinline__ unsigned int umin_(unsigned int a, unsigned int b) { return a < b ? a : b; }
__device__ __forceinline__ unsigned int umax_(unsigned int a, unsigned int b) { return a > b ? a : b; }

// branchless sorted-insert (ascending): 2 VALU ops/slot, no divergence.
template <int K>
__device__ __forceinline__ void pushk_b(unsigned int x, unsigned int (&l)[K]) {
    unsigned int prev = l[0];
    l[0] = umin_(l[0], x);
#pragma unroll
    for (int i = 1; i < K; ++i) {
        unsigned int cur = l[i];
        l[i] = umin_(umax_(x, prev), cur);
        prev = cur;
    }
}

// branchy insert (serial contexts: cheap reject dominates)
template <int K>
__device__ __forceinline__ void pushk(unsigned int k, unsigned int (&lst)[K]) {
    if (k >= lst[K - 1]) return;
    lst[K - 1] = k;
#pragma unroll
    for (int p = K - 1; p > 0; --p) {
        if (lst[p] < lst[p - 1]) {
            unsigned int t = lst[p]; lst[p] = lst[p - 1]; lst[p - 1] = t;
        }
    }
}

template <int K>
__device__ __forceinline__ void push(float d, int gi, float (&bd)[K], int (&bi)[K]) {
    if (d > bd[K - 1] || (d == bd[K - 1] && gi >= bi[K - 1])) return;
    bd[K - 1] = d; bi[K - 1] = gi;
#pragma unroll
    for (int p = K - 1; p > 0; --p) {
        bool sw = (bd[p] < bd[p - 1]) || (bd[p] == bd[p - 1] && bi[p] < bi[p - 1]);
        if (sw) {
            float td = bd[p]; bd[p] = bd[p - 1]; bd[p - 1] = td;
            int   ti = bi[p]; bi[p] = bi[p - 1]; bi[p - 1] = ti;
        }
    }
}

__global__ void cvt_bf16_kernel(const float* __restrict__ src,
                                unsigned short* __restrict__ dst, int n8) {
    int i = blockIdx.x * blockDim.x + threadIdx.x;
    if (i >= n8) return;
    const float4* s = (const float4*)src;
    float4 a0 = s[i * 2], a1 = s[i * 2 + 1];
    bf16x8 h;
    h[0] = (short)f2b(a0.x); h[1] = (short)f2b(a0.y);
    h[2] = (short)f2b(a0.z); h[3] = (short)f2b(a0.w);
    h[4] = (short)f2b(a1.x); h[5] = (short)f2b(a1.y);
    h[6] = (short)f2b(a1.z); h[7] = (short)f2b(a1.w);
    *(bf16x8*)(dst + (size_t)i * 8) = h;
}

__global__ void ysq_kernel(const float* __restrict__ Y, float* __restrict__ ysq) {
    int row  = (blockIdx.x * blockDim.x + threadIdx.x) >> 6;
    int lane = threadIdx.x & 63;
    if (row >= NY) return;
    const float4* yr = reinterpret_cast<const float4*>(Y + (size_t)row * DIM);
    double s = 0.0;
#pragma unroll
    for (int i = 0; i < 2; ++i) {
        float4 v = yr[lane + 64 * i];
        s += (double)v.x * v.x + (double)v.y * v.y + (double)v.z * v.z + (double)v.w * v.w;
    }
#pragma unroll
    for (int off = 32; off > 0; off >>= 1) s += __shfl_xor(s, off, 64);
    if (lane == 0) ysq[row] = (float)s;
}

// Coarse: r11 kernel (128x128 tile, dbuf, one barrier/K-step, X/Y L2 remap)
// + branchless top-6 lane lists (r13 change).
__global__ __launch_bounds__(256, 2) void knn_coarse_fast(
        const unsigned short* __restrict__ Xb, const unsigned short* __restrict__ Yb,
        const float* __restrict__ ysq,
        unsigned int* __restrict__ cand_k) {
    __shared__ __align__(16) char smem[65536];
    char* As = smem;
    char* Bs = smem + 32768;

    const int tid  = threadIdx.x;
    const int lane = tid & 63;
    const int w    = tid >> 6;
    const int l15  = lane & 15;
    const int lg   = lane >> 4;              // 0..3
    const int xcd  = blockIdx.x;             // 0..7 (linear%8 == blockIdx.x)
    const int s_   = blockIdx.y;             // 0..63
    const int z    = blockIdx.z;             // 0..3
    const int row0  = (xcd * 8 + (s_ & 7)) * BN;   // X tile (8 per XCD resident)
    const int yseg  = s_ >> 3;               // 0..7
    const int ybase = yseg * (NY / NSEG) + z * COLS_PER_CHUNK;
    const int slot  = yseg * NZ + z;         // 0..31 candidate slot
    const int m0 = (w >> 1) * 64;            // wave quadrant: Y side
    const int n0 = (w & 1) * 64;             //                X side

    const int srow = lane >> 3;                     // 0..7
    const int scb  = ((lane & 7) ^ srow) << 4;      // swizzled source chunk
    const char* pXbase = (const char*)Xb
        + ((size_t)(row0 + w * 32 + srow) << 10) + scb;

#define STAGE(tt, kcc, buf)                                                      \
    {                                                                            \
        const char* pY_ = (const char*)Yb                                        \
            + ((size_t)(ybase + (tt) * BM + w * 32 + srow) << 10)                \
            + ((kcc) << 7) + scb;                                                \
        const char* pX_ = pXbase + ((kcc) << 7);                                 \
        char* dA_ = As + ((buf) << 14) + (w << 12);                              \
        char* dB_ = Bs + ((buf) << 14) + (w << 12);                              \
        _Pragma("unroll")                                                        \
        for (int q = 0; q < 4; ++q) {                                            \
            __builtin_amdgcn_global_load_lds(AS1(pY_ + ((size_t)(q * 8) << 10)), \
                                             AS3(dA_ + (q << 10)), 16, 0, 0);    \
            __builtin_amdgcn_global_load_lds(AS1(pX_ + ((size_t)(q * 8) << 10)), \
                                             AS3(dB_ + (q << 10)), 16, 0, 0);    \
        }                                                                        \
    }

    unsigned int kb_[4][LPT];
#pragma unroll
    for (int nf = 0; nf < 4; ++nf)
#pragma unroll
        for (int m = 0; m < LPT; ++m) kb_[nf][m] = 0xffffffffu;

    STAGE(0, 0, 0);   // prologue: 8 loads in flight

    for (int t = 0; t < TILES; ++t) {
        const int ytile0 = ybase + t * BM;

        // ysq for the epilogue (asm: stays in our FIFO; drained by kc=1 vmcnt(0))
        f32x4 yv0, yv1, yv2, yv3;
        {
            const float* yp = ysq + ytile0 + m0 + lg * 4;
            asm volatile("global_load_dwordx4 %0, %1, off" : "=v"(yv0) : "v"(yp));
            asm volatile("global_load_dwordx4 %0, %1, off" : "=v"(yv1) : "v"(yp + 16));
            asm volatile("global_load_dwordx4 %0, %1, off" : "=v"(yv2) : "v"(yp + 32));
            asm volatile("global_load_dwordx4 %0, %1, off" : "=v"(yv3) : "v"(yp + 48));
        }

        f32x4 acc[4][4];
#pragma unroll
        for (int i = 0; i < 4; ++i)
#pragma unroll
            for (int j = 0; j < 4; ++j) acc[i][j] = (f32x4){0.f, 0.f, 0.f, 0.f};

#pragma unroll
        for (int kc = 0; kc < 8; ++kc) {
            const int buf = kc & 1;
            if (kc == 0) asm volatile("s_waitcnt vmcnt(4)" ::: "memory");
            else         asm volatile("s_waitcnt vmcnt(0)" ::: "memory");
            __builtin_amdgcn_sched_barrier(0);
            __builtin_amdgcn_s_barrier();
            if (kc < 7) {
                STAGE(t, kc + 1, buf ^ 1);
            } else if (t + 1 < TILES) {
                STAGE(t + 1, 0, buf ^ 1);
            }

            const char* Ab = As + (buf << 14);
            const char* Bb = Bs + (buf << 14);
#pragma unroll
            for (int kk = 0; kk < 2; ++kk) {
                const int kbyte = kk * 64 + lg * 16;
                const int sw = kbyte ^ ((l15 & 7) << 4);
                bf16x8 af[4], bf[4];
#pragma unroll
                for (int mf = 0; mf < 4; ++mf)
                    af[mf] = *(const bf16x8*)(Ab + ((m0 + mf * 16 + l15) << 7) + sw);
#pragma unroll
                for (int nf = 0; nf < 4; ++nf)
                    bf[nf] = *(const bf16x8*)(Bb + ((n0 + nf * 16 + l15) << 7) + sw);
                __builtin_amdgcn_s_setprio(1);
#pragma unroll
                for (int mf = 0; mf < 4; ++mf)
#pragma unroll
                    for (int nf = 0; nf < 4; ++nf)
                        acc[mf][nf] = __builtin_amdgcn_mfma_f32_16x16x32_bf16(
                            af[mf], bf[nf], acc[mf][nf], 0, 0, 0);
                __builtin_amdgcn_s_setprio(0);
            }
        }

        // epilogue: keys = (trunc(32*(ysq - 2*dot)) << 16) | yi, branchless insert
#pragma unroll
        for (int mf = 0; mf < 4; ++mf) {
            const int gib = ytile0 + m0 + mf * 16 + lg * 4;
            const f32x4 yv = (mf == 0) ? yv0 : (mf == 1) ? yv1 : (mf == 2) ? yv2 : yv3;
#pragma unroll
            for (int nf = 0; nf < 4; ++nf) {
#pragma unroll
                for (int j = 0; j < 4; ++j) {
                    float d32 = fmaf(acc[mf][nf][j], -64.f, yv[j] * 32.f);
                    d32 = fminf(fmaxf(d32, 0.f), 65535.f);
                    pushk_b<LPT>(((unsigned int)d32 << 16) | (unsigned int)(gib + j),
                                 kb_[nf]);
                }
            }
        }
    }
#undef STAGE

    // ---- merge 8 lane-lists per X row (reuses smem) ----
    __syncthreads();
    unsigned int* mbuf = (unsigned int*)smem;   // 128 rows x 50 dwords = 25.6 KB
    const int mslot = (w >> 1) * 4 + lg;        // 0..7
#pragma unroll
    for (int nf = 0; nf < 4; ++nf) {
        const int r = n0 + nf * 16 + l15;
#pragma unroll
        for (int e = 0; e < LPT; ++e)
            mbuf[r * 50 + mslot * LPT + e] = kb_[nf][e];
    }
    __syncthreads();
    if (tid < 128) {
        unsigned int mk[KEEP];
#pragma unroll
        for (int m = 0; m < KEEP; ++m) mk[m] = 0xffffffffu;
        for (int s2 = 0; s2 < 8; ++s2)
#pragma unroll
            for (int e = 0; e < LPT; ++e)
                pushk_b<KEEP>(mbuf[tid * 50 + s2 * LPT + e], mk);
        const int row = row0 + tid;
        unsigned int* co = cand_k + (size_t)row * NCAND + slot * KEEP;
#pragma unroll
        for (int m = 0; m < KEEP; ++m) co[m] = mk[m];
    }
}

// Rescore: coarse top-32 of 256 packed keys, then BIT-EXACT round-1 arithmetic.
__global__ __launch_bounds__(256) void knn_rescore(
        const float* __restrict__ X, const float* __restrict__ Y,
        const float* __restrict__ ysq,
        const unsigned int* __restrict__ cand_k,
        int* __restrict__ out) {
    __shared__ unsigned int ck[8][NCAND];
    __shared__ int   rci[8][RESC];
    __shared__ float rd[8][RESC];

    const int tid  = threadIdx.x;
    const int row0 = blockIdx.x * 8;

#pragma unroll
    for (int q = 0; q < 8; ++q) {
        const int idx = q * 256 + tid;       // 0..2047
        const int r = idx >> 8, j = idx & 255;
        ck[r][j] = cand_k[(size_t)(row0 + r) * NCAND + j];
    }
    __syncthreads();

    if (tid < 8) {
        unsigned int mk[RESC];
#pragma unroll
        for (int m = 0; m < RESC; ++m) mk[m] = 0xffffffffu;
        for (int j = 0; j < NCAND; ++j) pushk<RESC>(ck[tid][j], mk);
#pragma unroll
        for (int m = 0; m < RESC; ++m) rci[tid][m] = (int)(mk[m] & 0xffffu);
    }
    __syncthreads();

    {
        const int r = tid >> 5, c = tid & 31;
        const int row = row0 + r;
        const int yi = rci[r][c];
        const float* xr = X + (size_t)row * DIM;
        const float* yr = Y + (size_t)yi * DIM;
        double acc64 = 0.0;
        for (int kc = 0; kc < DIM; kc += 64) {
            float acc = 0.f;
#pragma unroll
            for (int k4 = 0; k4 < 16; ++k4) {
                float4 xv = *(const float4*)(xr + kc + k4 * 4);
                float4 yv = *(const float4*)(yr + kc + k4 * 4);
                acc = fmaf(xv.x, yv.x, acc);
                acc = fmaf(xv.y, yv.y, acc);
                acc = fmaf(xv.z, yv.z, acc);
                acc = fmaf(xv.w, yv.w, acc);
            }
            acc64 += (double)acc;
        }
        rd[r][c] = (float)((double)ysq[yi] - 2.0 * acc64);
    }
    __syncthreads();

    if (tid < 8) {
        float fd[KNN]; int fi[KNN];
#pragma unroll
        for (int m = 0; m < KNN; ++m) { fd[m] = INFINITY; fi[m] = 0x7fffffff; }
        for (int j = 0; j < RESC; ++j) push<KNN>(rd[tid][j], rci[tid][j], fd, fi);
        const int row = row0 + tid;
#pragma unroll
        for (int m = 0; m < KNN; ++m) out[row * KNN + m] = fi[m];
    }
}

extern "C" void kernel_launch(void* const* d_in, const int* in_sizes, int n_in,
                              void* d_out, int out_size, void* d_ws, size_t ws_size,
                              hipStream_t stream) {
    const float* X = (const float*)d_in[0];   // [8192, 512]
    const float* Y = (const float*)d_in[1];   // [65536, 512]
    int* out = (int*)d_out;                   // [8192, 8] int32

    char* ws = (char*)d_ws;
    float* ysq           = (float*)ws;                              // 256 KB
    unsigned int* cand_k = (unsigned int*)(ws + 262144);            // 8 MB
    size_t off = 262144 + (size_t)NX * NCAND * 4;
    unsigned short* Xbf = (unsigned short*)(ws + off);              // 8 MB
    unsigned short* Ybf = (unsigned short*)(ws + off + (size_t)NX * DIM * 2);  // 64 MB

    ysq_kernel<<<NY / 4, 256, 0, stream>>>(Y, ysq);
    cvt_bf16_kernel<<<(NX * DIM / 8) / 256, 256, 0, stream>>>(X, Xbf, NX * DIM / 8);
    cvt_bf16_kernel<<<(NY * DIM / 8) / 256, 256, 0, stream>>>(Y, Ybf, NY * DIM / 8);

    dim3 g1(8, 64, NZ);   // 2048 blocks; linear%8 = blockIdx.x = xcd
    knn_coarse_fast<<<g1, 256, 0, stream>>>(Xbf, Ybf, ysq, cand_k);

    knn_rescore<<<NX / 8, 256, 0, stream>>>(X, Y, ysq, cand_k, out);
}